// Round 2
// baseline (80.539 us; speedup 1.0000x reference)
//
#include <hip/hip_runtime.h>
#include <math.h>

// NoiseGenerator R5b: exact two-kernel block-state decomposition.
//   out[n] = HP(LP(noise))[n] * env[n] * gain
//   State s=(y,z): s[n] = M s[n-1] + v x[n], M = [[a,0],[b(a-1),b]] (lower-tri,
//   operators are 3 floats, compose = 3 FMAs; powers of M commute).
//
// vs R4b (halo + LDS staging, ~30us device):
//  - NO halo: kernel1 publishes each block's exact zero-state end state E_b
//    (8 B) to scratch; kernel2 computes the exact block-incoming state
//    s0 = sum_{u<b} Q^{b-1-u} E_u  (Q = M^4096) redundantly per block via a
//    per-thread Horner over <=4 E entries (stride 256) + Q^tid weighting +
//    a 256-thread reduction. Stream order between the two launches gives
//    cross-XCD visibility (kernel boundary = device release/acquire).
//  - NO LDS data path: each thread holds its 16 samples in registers via
//    4x dwordx4 at 64B lane stride (a wave's 4 loads tile a dense 4KB
//    window; L1/L2 merge the lines). Stores are the same pattern in
//    reverse; L2 write-combines the 16B quadrants into full lines.
//  - Single true recurrence in kernel2 (correct start state) replaces the
//    zero-state + homogeneous superposition pair.
//  - LDS 21.5KB -> 64B; barriers 3 -> 2; no truncation error (exact).
//  - R5b hardening: scratch = d_ws only if ws_size suffices, else a
//    module-scope __device__ array (no dependence on harness workspace).

#define BLOCK 256
#define CHUNK 16
#define SAMP  (BLOCK * CHUNK)   // 4096 samples per block -> grid 1024 @ n=2^22
#define ESTG_CAP 4096           // fallback scratch: supports grid <= 2048

typedef float vfloat4 __attribute__((ext_vector_type(4)));
typedef float vfloat2 __attribute__((ext_vector_type(2)));

__device__ float Est_g[ESTG_CAP];   // loader-allocated fallback scratch

struct Op { float a, w, b; };   // [[a,0],[w,b]]
__device__ __forceinline__ Op opmul(Op A, Op B) {   // A*B
    Op C;
    C.a = A.a * B.a;
    C.w = fmaf(A.w, B.a, A.b * B.w);
    C.b = A.b * B.b;
    return C;
}

template<bool EMIT>
__global__ __launch_bounds__(BLOCK, 4) void ng_kernel(
    const float* __restrict__ params,
    const float* __restrict__ noise,
    float* __restrict__ out,
    float* __restrict__ EstArg,
    int n)
{
    __shared__ float swy[4], swz[4], ry[4], rz[4];

    float* __restrict__ Est = EstArg ? EstArg : Est_g;

    const int tid  = threadIdx.x;
    const int lane = tid & 63;
    const int wid  = tid >> 6;
    const int b    = blockIdx.x;
    const int g0   = b * SAMP + tid * CHUNK;

    const float a   = fminf(fmaxf(params[2], 1e-7f), 0.99f);
    const float bb  = fminf(fmaxf(params[3], 1e-7f), 0.99f);
    const float omc = 1.0f - a;

    // ---- prefetch E operands for the Horner (kernel2 only) ----
    // thread t owns exponents e = t + 256*j  (e <= b-1), i.e. u = b-1-e
    int nt = 0;
    vfloat2 Ev[4] = {{0.f,0.f},{0.f,0.f},{0.f,0.f},{0.f,0.f}};
    if (EMIT) {
        int em = b - 1 - tid;
        nt = (em >= 0) ? ((em >> 8) + 1) : 0;
        #pragma unroll
        for (int j = 0; j < 4; ++j) {
            if (j < nt) {
                int u = b - 1 - tid - (j << 8);
                Ev[j] = *(const vfloat2*)(Est + 2 * u);
            }
        }
    }

    // ---- per-thread x in registers: 4x float4, 64B lane stride ----
    vfloat4 xq[4];
    if (g0 + CHUNK <= n) {
        #pragma unroll
        for (int q = 0; q < 4; ++q)
            xq[q] = *(const vfloat4*)(noise + g0 + 4 * q);
    } else {
        #pragma unroll
        for (int q = 0; q < 4; ++q) {
            #pragma unroll
            for (int c = 0; c < 4; ++c) {
                int g = g0 + 4 * q + c;
                xq[q][c] = (g < n) ? noise[g] : 0.0f;
            }
        }
    }

    // ---- zero-state end state of own 16-sample chunk ----
    float yv = 0.0f, zv = 0.0f;
    #pragma unroll
    for (int j = 0; j < CHUNK; ++j) {
        float x  = xq[j >> 2][j & 3];
        float yn = fmaf(a, yv, omc * x);
        zv = bb * (zv + (yn - yv));
        yv = yn;
    }

    // ---- intra-wave Hillis-Steele scan (operator squaring) ----
    Op m1 = { a, bb * (a - 1.0f), bb };
    Op m2 = opmul(m1, m1), m4 = opmul(m2, m2), m8 = opmul(m4, m4);
    Op P  = opmul(m8, m8);          // M^16 = M^CHUNK
    Op O  = { 1.0f, 0.0f, 1.0f };   // M^(CHUNK*lane), built from pre-square P
    float cy = yv, cz = zv;
    #pragma unroll
    for (int k = 0; k < 6; ++k) {
        if (EMIT && ((lane >> k) & 1)) O = opmul(P, O);
        int d = 1 << k;
        float py = __shfl_up(cy, d, 64);
        float pz = __shfl_up(cz, d, 64);
        if (lane >= d) {
            cy = fmaf(P.a, py, cy);
            cz = fmaf(P.w, py, fmaf(P.b, pz, cz));
        }
        P = opmul(P, P);            // after loop: P = R = M^1024 (wave op)
    }
    if (lane == 63) { swy[wid] = cy; swz[wid] = cz; }
    __syncthreads();                // barrier 1

    // cross-wave zero-init prefix: state entering this wave (block-local)
    float pry = 0.0f, prz = 0.0f;
    for (int u = 0; u < wid; ++u) { // wave-uniform trip count
        float ny = fmaf(P.a, pry, swy[u]);
        float nz = fmaf(P.w, pry, fmaf(P.b, prz, swz[u]));
        pry = ny; prz = nz;
    }

    if (!EMIT) {
        // kernel1: publish block end state E_b = R*pref_3 + S_3
        if (tid == 255) {
            vfloat2 e;
            e.x = fmaf(P.a, pry, cy);
            e.y = fmaf(P.w, pry, fmaf(P.b, prz, cz));
            *(vfloat2*)(Est + 2 * b) = e;
        }
        return;
    }

    // ---- exclusive intra-wave value ----
    float ey = __shfl_up(cy, 1, 64);
    float ez = __shfl_up(cz, 1, 64);
    if (lane == 0) { ey = 0.0f; ez = 0.0f; }

    // ---- s0 = sum_{u<b} Q^{b-1-u} E_u,  Q = M^4096 ----
    Op R2 = opmul(P, P);            // M^2048
    Op Q  = opmul(R2, R2);          // M^4096
    Op Ot = { 1.0f, 0.0f, 1.0f };   // Q^tid
    Op cur = Q;
    #pragma unroll
    for (int k = 0; k < 8; ++k) {
        if ((tid >> k) & 1) Ot = opmul(cur, Ot);
        cur = opmul(cur, cur);      // after loop: cur = Q^256
    }
    float Hy = 0.0f, Hz = 0.0f;
    for (int j = nt - 1; j >= 4; --j) {          // general-n fallback (dead @ n=2^22)
        int u = b - 1 - tid - (j << 8);
        vfloat2 e = *(const vfloat2*)(Est + 2 * u);
        float t = fmaf(cur.a, Hy, e.x);
        Hz = fmaf(cur.w, Hy, fmaf(cur.b, Hz, e.y));
        Hy = t;
    }
    #pragma unroll
    for (int j = 3; j >= 0; --j) {
        if (j < nt) {
            float t = fmaf(cur.a, Hy, Ev[j].x);
            Hz = fmaf(cur.w, Hy, fmaf(cur.b, Hz, Ev[j].y));
            Hy = t;
        }
    }
    // weighted contribution Q^tid * H, then 256-thread sum-reduce
    float vy = Ot.a * Hy;
    float vz = fmaf(Ot.w, Hy, Ot.b * Hz);
    #pragma unroll
    for (int d = 1; d < 64; d <<= 1) {
        vy += __shfl_xor(vy, d, 64);
        vz += __shfl_xor(vz, d, 64);
    }
    if (lane == 0) { ry[wid] = vy; rz[wid] = vz; }
    __syncthreads();                // barrier 2
    float s0y = (ry[0] + ry[1]) + (ry[2] + ry[3]);
    float s0z = (rz[0] + rz[1]) + (rz[2] + rz[3]);

    // ---- thread start state: O*(R^wid*s0 + pref_wid) + excl ----
    float wy = s0y, wz = s0z;
    for (int u = 0; u < wid; ++u) { // R^wid * s0, wave-uniform
        float t = P.a * wy;
        wz = fmaf(P.w, wy, P.b * wz);
        wy = t;
    }
    wy += pry; wz += prz;
    float y0 = fmaf(O.a, wy, ey);
    float z0 = ez + fmaf(O.w, wy, O.b * wz);

    // ---- single true recurrence + envelope, store from registers ----
    const float attack = fmaxf(params[0], 1e-7f);
    const float decay  = fmaxf(params[1], 1e-7f);
    const float gain   = fmaxf(params[4], 1e-7f);
    const float inv    = 1.0f / (float)(n - 1);
    const float ia = -1.0f / attack;
    const float id = -1.0f / decay;
    const float t0 = (float)g0 * inv;           // g0 >= 0: no overflow branch
    float ea = __expf(ia * t0);                 // exp(-t/attack) running product
    float ed = __expf(id * t0) * gain;          // exp(-t/decay) * gain
    const float ra = __expf(ia * inv);
    const float rd = __expf(id * inv);

    vfloat4 oq[4];
    yv = y0; zv = z0;
    #pragma unroll
    for (int j = 0; j < CHUNK; ++j) {
        float x  = xq[j >> 2][j & 3];
        float yn = fmaf(a, yv, omc * x);
        zv = bb * (zv + (yn - yv));
        yv = yn;
        oq[j >> 2][j & 3] = zv * ((1.0f - ea) * ed);
        ea *= ra; ed *= rd;
    }
    if (g0 + CHUNK <= n) {
        #pragma unroll
        for (int q = 0; q < 4; ++q)
            *(vfloat4*)(out + g0 + 4 * q) = oq[q];
    } else {
        #pragma unroll
        for (int q = 0; q < 4; ++q) {
            #pragma unroll
            for (int c = 0; c < 4; ++c) {
                int g = g0 + 4 * q + c;
                if (g < n) out[g] = oq[q][c];
            }
        }
    }
}

extern "C" void kernel_launch(void* const* d_in, const int* in_sizes, int n_in,
                              void* d_out, int out_size, void* d_ws, size_t ws_size,
                              hipStream_t stream) {
    const float* params = (const float*)d_in[0];
    const float* noise  = (const float*)d_in[1];
    float* out = (float*)d_out;
    int n = in_sizes[1];
    int grid = (n + SAMP - 1) / SAMP;   // 1024 blocks @ n = 4194304
    // scratch: d_ws if the harness gave us enough, else module-scope array
    float* Est = (ws_size >= (size_t)(2 * grid) * sizeof(float))
                     ? (float*)d_ws : nullptr;   // nullptr -> Est_g in-kernel
    ng_kernel<false><<<grid, BLOCK, 0, stream>>>(params, noise, out, Est, n);
    ng_kernel<true ><<<grid, BLOCK, 0, stream>>>(params, noise, out, Est, n);
}